// Round 8
// baseline (140.197 us; speedup 1.0000x reference)
//
#include <hip/hip_runtime.h>
#include <stddef.h>

// ---------- types ----------
typedef __bf16 bf16x8 __attribute__((ext_vector_type(8)));
typedef __bf16 bf16x4 __attribute__((ext_vector_type(4)));
typedef _Float16 f16x4 __attribute__((ext_vector_type(4)));
typedef float  f32x4  __attribute__((ext_vector_type(4)));

#define MFMA16(a, b, c) __builtin_amdgcn_mfma_f32_16x16x32_bf16((a), (b), (c), 0, 0, 0)
#define MFMA16H(a, b, c) __builtin_amdgcn_mfma_f32_16x16x16f16((a), (b), (c), 0, 0, 0)

// async global->LDS, 16B per lane; LDS dest is wave-uniform base + lane*16
__device__ __forceinline__ void gload_lds16(const void* gsrc, void* ldst) {
    __builtin_amdgcn_global_load_lds(
        (__attribute__((address_space(1))) void*)gsrc,
        (__attribute__((address_space(3))) void*)ldst,
        16, 0, 0);
}

// ---------- K0: fused prep = fp32->bf16 cast of x  +  transpose+cast of both weights ----------
// x-cast: 4 float4/thread -> 768 blocks (was 3072 at 1/thread); grid 5376 -> 3072.
__global__ void prep_kernel(const float* __restrict__ x, __bf16* __restrict__ xbf,
                            const float* __restrict__ Wqkv, __bf16* __restrict__ WqkvT,
                            const float* __restrict__ Wproj, __bf16* __restrict__ WprojT) {
    __shared__ float tile[32][33];
    const int bx = blockIdx.x, tid = threadIdx.x;
    if (bx < 768) {                        // cast x: 786432 float4 groups, 4/thread
#pragma unroll
        for (int j = 0; j < 4; j++) {
            int i = bx * 1024 + j * 256 + tid;
            float4 v = ((const float4*)x)[i];
            bf16x4 o = {(__bf16)v.x, (__bf16)v.y, (__bf16)v.z, (__bf16)v.w};
            ((bf16x4*)xbf)[i] = o;
        }
        return;
    }
    const float* in; __bf16* out; int R, C, c0, r0;
    if (bx < 2496) { int bb = bx - 768;  in = Wqkv;  out = WqkvT;  R = 768; C = 2304;
                     c0 = (bb % 72) * 32; r0 = (bb / 72) * 32; }
    else           { int bb = bx - 2496; in = Wproj; out = WprojT; R = 768; C = 768;
                     c0 = (bb % 24) * 32; r0 = (bb / 24) * 32; }
    const int tx = tid & 31, ty = tid >> 5;    // 32 x 8
#pragma unroll
    for (int i = 0; i < 32; i += 8)
        tile[ty + i][tx] = in[(size_t)(r0 + ty + i) * C + c0 + tx];
    __syncthreads();
#pragma unroll
    for (int i = 0; i < 32; i += 8)
        out[(size_t)(c0 + ty + i) * R + r0 + tx] = (__bf16)tile[tx][ty + i];
}

// ---------- GEMM core: BM x BN tile, BK=64, 256 threads (4 waves, each (BM/2)x(BN/2)) ----------
// POST-MORTEM R5 (BK=32 dbuf, +7.3us): 32-elem LDS rows (64 B) alias banks every 2 rows
// -> frag ds_read_b128 went 4-way-conflicted; and the 12-MFMA compute phase (~130 cyc)
// can't cover L3-hit staging latency (~400+ cyc) anyway since __syncthreads always
// drains vmcnt(0). This 2-barrier BK=64 single-buffer core with 128B rows + 8-chunk
// XOR swizzle is the measured local optimum — co-resident blocks (3/CU) hide the drain.
// LDS rows are 64 elems (8 chunks of 16B); chunk c of row r stored at slot c ^ (r&7).
template<int BM, int BN>
__device__ __forceinline__ void gemm_core_bk64(
    const __bf16* __restrict__ A, const __bf16* __restrict__ Bt, int K,
    int m0, int n0, __bf16* aT, __bf16* bT, f32x4 (&acc)[BM/32][BN/32]) {
    const int tid  = threadIdx.x;
    const int wid  = tid >> 6, lane = tid & 63;
    const int quad = lane >> 4, l16 = lane & 15;
    const int wm = (wid >> 1) * (BM / 2), wn = (wid & 1) * (BN / 2);
    const int r_in = lane >> 3;                    // 0..7
    const int cswz = ((lane & 7) ^ r_in) * 8;      // swizzled k-chunk offset (elems)
    const __bf16* gA = A  + (size_t)(m0 + wid * 8 + r_in) * K + cswz;
    const __bf16* gB = Bt + (size_t)(n0 + wid * 8 + r_in) * K + cswz;
    const int sA = (l16 & 7);
    for (int k0 = 0; k0 < K; k0 += 64) {
        __syncthreads();
#pragma unroll
        for (int j = 0; j < BM / 32; j++)
            gload_lds16(gA + (size_t)(j * 32) * K + k0, aT + (j * 32 + wid * 8) * 64);
#pragma unroll
        for (int j = 0; j < BN / 32; j++)
            gload_lds16(gB + (size_t)(j * 32) * K + k0, bT + (j * 32 + wid * 8) * 64);
        __syncthreads();
#pragma unroll
        for (int kh = 0; kh < 2; kh++) {
            bf16x8 af[BM / 32], bfr[BN / 32];
            const int slot = ((kh * 4 + quad) ^ sA) << 3;
#pragma unroll
            for (int t = 0; t < BM / 32; t++)
                af[t]  = *(const bf16x8*)(aT + (wm + t * 16 + l16) * 64 + slot);
#pragma unroll
            for (int t = 0; t < BN / 32; t++)
                bfr[t] = *(const bf16x8*)(bT + (wn + t * 16 + l16) * 64 + slot);
#pragma unroll
            for (int rt = 0; rt < BM / 32; rt++)
#pragma unroll
                for (int ct = 0; ct < BN / 32; ct++)
                    acc[rt][ct] = MFMA16(af[rt], bfr[ct], acc[rt][ct]);
        }
    }
}

// ---------- K1: QKV GEMM, epilogue scatters to q/k (bh,s,d) bf16 and vT (bh,d,s) f16 ----------
// 128x96 tile, grid (32,24) = 768 blocks = 3/CU uniform. BN=96 divides 768 -> `which`
// is BLOCK-uniform: by 0-7 pure-q, 8-15 pure-k, 16-23 pure-v.
// q/k blocks (2/3 of grid) previously issued 48 scalar 2B stores/thread (4x32B segments
// per wave-inst, 192 segs). New: LDS-transpose epilogue — stage the 128x96 block tile
// in (s,d) bf16 (stride 104: 208B rows = 16B-aligned b128 reads, 2-way write alias =
// free), one barrier, then 6x {ds_read_b128 + global_store_dwordx4} per thread with
// consecutive threads on consecutive 8-d groups (~192B runs). Pure data movement:
// bit-identical output (k keeps fp32*KSCALE-then-cast order).
// K is pre-scaled by 0.125*log2e (K only feeds QK^T) so attn inner loop is bare exp2.
__global__ __launch_bounds__(256, 3)
void gemm_qkv_kernel(const __bf16* __restrict__ A, const __bf16* __restrict__ Bt,
                     __bf16* __restrict__ qb, __bf16* __restrict__ kb,
                     _Float16* __restrict__ vtb) {
    __shared__ __bf16 smem[14336];                  // aT 8192 + bT 6144 (28 KB)
    __bf16* aT = smem;
    __bf16* bT = smem + 8192;
    f32x4 acc[4][3];
#pragma unroll
    for (int i = 0; i < 4; i++)
#pragma unroll
        for (int j = 0; j < 3; j++) { f32x4 z = {0.f, 0.f, 0.f, 0.f}; acc[i][j] = z; }
    const int m0 = blockIdx.x * 128, n0 = blockIdx.y * 96;
    gemm_core_bk64<128, 96>(A, Bt, 768, m0, n0, aT, bT, acc);
    const int tid = threadIdx.x, wid = tid >> 6, lane = tid & 63;
    const int quad = lane >> 4, l16 = lane & 15;
    const int wm = (wid >> 1) * 64, wn = (wid & 1) * 48;
    const float KSCALE = 0.18033688f;   // 0.125 * log2(e)

    if (n0 >= 1536) {
        // ---- pure-v block: packed f16x4 stores along s (unchanged path) ----
#pragma unroll
        for (int rt = 0; rt < 4; rt++)
#pragma unroll
            for (int ct = 0; ct < 3; ct++) {
                const int ng = n0 + wn + ct * 16 + l16;
                const int rem = ng - 1536;
                const int hh = rem >> 6, d = rem & 63;
                const int mgb = m0 + wm + rt * 16 + quad * 4;
                const int b = mgb >> 10, s = mgb & 1023;
                const int bh = b * 12 + hh;
                f16x4 vv = {(_Float16)acc[rt][ct][0], (_Float16)acc[rt][ct][1],
                            (_Float16)acc[rt][ct][2], (_Float16)acc[rt][ct][3]};
                *(f16x4*)&vtb[((size_t)bh * 64 + d) * 1024 + s] = vv;
            }
        return;
    }

    // ---- pure-q or pure-k block: LDS-transpose epilogue ----
    const bool isk = (n0 >= 768);
    const float sc = isk ? KSCALE : 1.0f;           // *1.0f is IEEE-exact for q
    // stage block tile (s 0..127, d-local 0..95), row stride 104 elems (208 B)
#pragma unroll
    for (int rt = 0; rt < 4; rt++)
#pragma unroll
        for (int ct = 0; ct < 3; ct++)
#pragma unroll
            for (int r = 0; r < 4; r++)
                smem[(wm + rt * 16 + quad * 4 + r) * 104 + wn + ct * 16 + l16] =
                    (__bf16)(acc[rt][ct][r] * sc);
    __syncthreads();
    __bf16* dst = isk ? kb : qb;
    const int nrel = n0 - (isk ? 768 : 0);          // 0..672, block-uniform
    const int b_ = m0 >> 10;                        // 128 | 1024 -> block-uniform
    const size_t base = ((size_t)b_ * 12) * 65536 + (size_t)(m0 & 1023) * 64;
    // 128 rows x 12 d-groups = 1536 b128 stores, 6 per thread; consecutive threads
    // cover consecutive d-groups -> ~192B contiguous runs
#pragma unroll
    for (int i = 0; i < 6; i++) {
        const unsigned flat = (unsigned)(i * 256 + tid);
        const unsigned s = flat / 12u, g = flat - s * 12u;
        const int ngr = nrel + (int)g * 8;          // 8-groups never straddle mod-64
        const int hh = ngr >> 6, d = ngr & 63;
        bf16x8 vv = *(const bf16x8*)(smem + s * 104 + g * 8);
        *(bf16x8*)&dst[base + (size_t)hh * 65536 + (size_t)s * 64 + d] = vv;
    }
}

// ---------- K4: proj GEMM + bias, fp32 out ----------
// 64x64 tile, grid (64,12) = 768 blocks = 3/CU uniform.
__global__ __launch_bounds__(256, 3)
void gemm_proj_kernel(const __bf16* __restrict__ A, const __bf16* __restrict__ Bt,
                      const float* __restrict__ bias, float* __restrict__ out) {
    __shared__ __bf16 aT[4096], bT[4096];
    f32x4 acc[2][2];
#pragma unroll
    for (int i = 0; i < 2; i++)
#pragma unroll
        for (int j = 0; j < 2; j++) { f32x4 z = {0.f, 0.f, 0.f, 0.f}; acc[i][j] = z; }
    const int m0 = blockIdx.x * 64, n0 = blockIdx.y * 64;
    gemm_core_bk64<64, 64>(A, Bt, 768, m0, n0, aT, bT, acc);
    const int tid = threadIdx.x, wid = tid >> 6, lane = tid & 63;
    const int quad = lane >> 4, l16 = lane & 15;
    const int wm = (wid >> 1) * 32, wn = (wid & 1) * 32;
#pragma unroll
    for (int rt = 0; rt < 2; rt++)
#pragma unroll
        for (int ct = 0; ct < 2; ct++) {
            const int ng = n0 + wn + ct * 16 + l16;
            const float bb = bias[ng];
#pragma unroll
            for (int r = 0; r < 4; r++) {
                const int mg = m0 + wm + rt * 16 + quad * 4 + r;
                out[(size_t)mg * 768 + ng] = acc[rt][ct][r] + bb;
            }
        }
}

// ---------- K3: attention v7.3 — v7 partition, exp2 softmax, bias in MFMA C-operand ----------
// grid (48 bh, 16 qt), block 256 (4 waves), Q-tile 64, 16 rows/wave.
// bh-fast grid is XCD-optimal (48 % 8 == 0 -> 6 bh x 128 KB/XCD, L2-fit, qt-readers
// co-located). The softmax bias (bhc + bw) is seeded as the S^T MFMA's C-init.
// S^T = MFMA(K-frag, Q-frag): C-layout col=l16=qrow, row=quad*4+r=key — exactly the
// B-frag layout of mfma_f32_16x16x16f16 (k=quad*4+j) -> PV from registers, no P LDS trip.
// K LDS: (key,d) bf16, chunk c of row stored at c^(key&7). V LDS: (d,key) f16, chunk
// kc of row d stored at kc^(d&7) -> b64 A-frag reads are 2-way conflict (free).
// Phase A overlays the K dbuf (16 KB) with Dw[wave][16r][64j] fp32 for rel_w gather.
__global__ __launch_bounds__(256, 3)
void attn_kernel(const __bf16* __restrict__ q, const __bf16* __restrict__ kk,
                 const _Float16* __restrict__ vt, const float* __restrict__ rph,
                 const float* __restrict__ rpw, __bf16* __restrict__ aout) {
    __shared__ __bf16   kbuf2[2][4096];
    __shared__ _Float16 vbuf2[2][4096];
    __shared__ float    relh[64][33];
    const int tid = threadIdx.x, wid = tid >> 6, lane = tid & 63;
    const int quad = lane >> 4, l16 = lane & 15;
    const int bh = blockIdx.x, qt = blockIdx.y;
    const int b = bh / 12, hh = bh - b * 12;
    const int q0 = qt * 64;
    const int w0 = wid * 16;               // wave's first row within the tile
    const int h = qt * 2 + (wid >> 1);     // wave-uniform h coordinate
    const float LOG2E = 1.44269504f;

    // Q fragments: lane holds Q[w0+l16][quad*8+j] — B-frag for S^T, A-frag for Phase A
    const __bf16* qp = q + ((size_t)bh * 1024 + q0 + w0 + l16) * 64;
    bf16x8 aq0 = *(const bf16x8*)(qp + quad * 8);
    bf16x8 aq1 = *(const bf16x8*)(qp + 32 + quad * 8);

    // ---- Phase A: rel_w D-GEMM (Toeplitz) + rel_h GEMM, via MFMA; tables pre-scaled
    // by log2e so the main loop uses native exp2. ----
    float* Dw = ((float*)kbuf2) + wid * 1024;   // 16 rows x 64 cols fp32, per wave
#pragma unroll
    for (int ct = 0; ct < 4; ct++) {
        int j = ct * 16 + l16; if (j > 62) j = 62;
        const float* tb = rpw + (size_t)j * 64;
        float4 t0 = *(const float4*)(tb + quad * 8);
        float4 t1 = *(const float4*)(tb + quad * 8 + 4);
        float4 t2 = *(const float4*)(tb + 32 + quad * 8);
        float4 t3 = *(const float4*)(tb + 32 + quad * 8 + 4);
        bf16x8 b0 = {(__bf16)(t0.x*LOG2E), (__bf16)(t0.y*LOG2E), (__bf16)(t0.z*LOG2E), (__bf16)(t0.w*LOG2E),
                     (__bf16)(t1.x*LOG2E), (__bf16)(t1.y*LOG2E), (__bf16)(t1.z*LOG2E), (__bf16)(t1.w*LOG2E)};
        bf16x8 b1 = {(__bf16)(t2.x*LOG2E), (__bf16)(t2.y*LOG2E), (__bf16)(t2.z*LOG2E), (__bf16)(t2.w*LOG2E),
                     (__bf16)(t3.x*LOG2E), (__bf16)(t3.y*LOG2E), (__bf16)(t3.z*LOG2E), (__bf16)(t3.w*LOG2E)};
        f32x4 z = {0.f, 0.f, 0.f, 0.f};
        z = MFMA16(aq0, b0, z);
        z = MFMA16(aq1, b1, z);
#pragma unroll
        for (int i = 0; i < 4; i++)
            Dw[(quad * 4 + i) * 64 + ct * 16 + l16] = z[i];
    }
#pragma unroll
    for (int ct = 0; ct < 2; ct++) {
        const int tr = h - (ct * 16 + l16) + 31;     // in [0,62]
        const float* tb = rph + (size_t)tr * 64;
        float4 t0 = *(const float4*)(tb + quad * 8);
        float4 t1 = *(const float4*)(tb + quad * 8 + 4);
        float4 t2 = *(const float4*)(tb + 32 + quad * 8);
        float4 t3 = *(const float4*)(tb + 32 + quad * 8 + 4);
        bf16x8 b0 = {(__bf16)(t0.x*LOG2E), (__bf16)(t0.y*LOG2E), (__bf16)(t0.z*LOG2E), (__bf16)(t0.w*LOG2E),
                     (__bf16)(t1.x*LOG2E), (__bf16)(t1.y*LOG2E), (__bf16)(t1.z*LOG2E), (__bf16)(t1.w*LOG2E)};
        bf16x8 b1 = {(__bf16)(t2.x*LOG2E), (__bf16)(t2.y*LOG2E), (__bf16)(t2.z*LOG2E), (__bf16)(t2.w*LOG2E),
                     (__bf16)(t3.x*LOG2E), (__bf16)(t3.y*LOG2E), (__bf16)(t3.z*LOG2E), (__bf16)(t3.w*LOG2E)};
        f32x4 z = {0.f, 0.f, 0.f, 0.f};
        z = MFMA16(aq0, b0, z);
        z = MFMA16(aq1, b1, z);
#pragma unroll
        for (int i = 0; i < 4; i++)
            relh[w0 + quad * 4 + i][ct * 16 + l16] = z[i];
    }
    // gather rel_w biases for lane's qrow (= w0+l16): kw = hf*16 + quad*4 + r
    const int wq = (wid & 1) * 16 + l16;           // w coordinate of lane's qrow
    float bw[2][4];
#pragma unroll
    for (int hf = 0; hf < 2; hf++)
#pragma unroll
        for (int r = 0; r < 4; r++)
            bw[hf][r] = Dw[l16 * 64 + wq + 31 - hf * 16 - quad * 4 - r];
    __syncthreads();   // all gathers done before staging overwrites the Dw overlay

    // ---- main flash loop ----
    f32x4 lacc = {0.f, 0.f, 0.f, 0.f};    // 4 parallel row-sum chains (by r)
    f32x4 o_acc[4];
#pragma unroll
    for (int t = 0; t < 4; t++) { f32x4 z = {0.f, 0.f, 0.f, 0.f}; o_acc[t] = z; }

    const __bf16*   kg0 = kk + (size_t)bh * 65536;
    const _Float16* vg0 = vt + (size_t)bh * 65536;
    const int cbase = wid * 2;                         // 4 waves stage 2 chunks each
    const int srow = lane >> 3;
    const int scol = ((lane & 7) ^ srow) * 8;          // swizzled chunk (8 elems of 16B/8)
    const int swz0 = ((quad ^ (l16 & 7)) << 3);
    const int swz1 = (((quad | 4) ^ (l16 & 7)) << 3);
    const int l7 = l16 & 7, qhi = quad >> 1, qlo = (quad & 1) * 4;

    auto stage = [&](int buf, int kt) {
        const __bf16*   kg = kg0 + kt * 4096;
        const _Float16* vg = vg0 + kt * 64;
        __bf16*   kb_ = &kbuf2[buf][0];
        _Float16* vb_ = &vbuf2[buf][0];
#pragma unroll
        for (int j = 0; j < 2; j++) {
            const int c = cbase + j;
            gload_lds16(kg + (c * 8 + srow) * 64 + scol, kb_ + c * 512);
            gload_lds16(vg + (size_t)(c * 8 + srow) * 1024 + scol, vb_ + c * 512);
        }
    };

    stage(0, 0);
    for (int kt = 0; kt < 16; kt++) {
        const int cur = kt & 1;
        __syncthreads();                 // drains cur's staging
        if (kt < 15) stage(1 - cur, kt + 1);
        const __bf16*   kbuf = &kbuf2[cur][0];
        const _Float16* vbuf = &vbuf2[cur][0];

        // per-iter bias in S^T C-layout: elem r of (ct) = bh(ct>>1) + bw[ct&1][r]
        const float bh0 = relh[w0 + l16][kt * 2];
        const float bh1 = relh[w0 + l16][kt * 2 + 1];
        f32x4 biasC[2][2];
#pragma unroll
        for (int lo = 0; lo < 2; lo++)
#pragma unroll
            for (int r = 0; r < 4; r++) {
                biasC[0][lo][r] = bh0 + bw[lo][r];
                biasC[1][lo][r] = bh1 + bw[lo][r];
            }

        // S^T = K-frag (A) x Q-frag (B), accumulated onto the bias (C-init);
        // K already carries 0.125*log2e
        f32x4 sacc[4];
#pragma unroll
        for (int ct = 0; ct < 4; ct++) {
            const int key = ct * 16 + l16;
            bf16x8 bk0 = *(const bf16x8*)(kbuf + key * 64 + swz0);
            bf16x8 bk1 = *(const bf16x8*)(kbuf + key * 64 + swz1);
            f32x4 z = biasC[ct >> 1][ct & 1];
            z = MFMA16(bk0, aq0, z);
            z = MFMA16(bk1, aq1, z);
            sacc[ct] = z;
        }

        // exp2 directly on biased scores; pack P^T fragments (f16) from registers
        f16x4 pf[4];
#pragma unroll
        for (int ct = 0; ct < 4; ct++)
#pragma unroll
            for (int r = 0; r < 4; r++) {
                float p = __builtin_amdgcn_exp2f(sacc[ct][r]);
                lacc[r] += p;
                pf[ct][r] = (_Float16)p;
            }

        // O^T += V^T * P^T  (16x16x16 f16 MFMAs, V A-frags via b64 LDS reads)
#pragma unroll
        for (int dt = 0; dt < 4; dt++) {
            const int vrow = (dt * 16 + l16) * 64;
#pragma unroll
            for (int ct = 0; ct < 4; ct++) {
                const int slot = (ct * 2 + qhi) ^ l7;
                f16x4 vf = *(const f16x4*)(vbuf + vrow + slot * 8 + qlo);
                o_acc[dt] = MFMA16H(vf, pf[ct], o_acc[dt]);
            }
        }
    }

    // merge the 4 chains, reduce across the 4 quads holding the same qrow, normalize
    float l_run = (lacc[0] + lacc[1]) + (lacc[2] + lacc[3]);
    l_run += __shfl_xor(l_run, 16);
    l_run += __shfl_xor(l_run, 32);
    const float inv = 1.f / l_run;
    const int srow_o = q0 + w0 + l16;
#pragma unroll
    for (int dt = 0; dt < 4; dt++) {
        bf16x4 ov = {(__bf16)(o_acc[dt][0] * inv), (__bf16)(o_acc[dt][1] * inv),
                     (__bf16)(o_acc[dt][2] * inv), (__bf16)(o_acc[dt][3] * inv)};
        *(bf16x4*)&aout[((size_t)b * 1024 + srow_o) * 768 + hh * 64 + dt * 16 + quad * 4] = ov;
    }
}

// ---------- launch ----------
extern "C" void kernel_launch(void* const* d_in, const int* in_sizes, int n_in,
                              void* d_out, int out_size, void* d_ws, size_t ws_size,
                              hipStream_t stream) {
    const float* x     = (const float*)d_in[0];
    const float* Wqkv  = (const float*)d_in[1];
    const float* Wproj = (const float*)d_in[2];
    const float* bproj = (const float*)d_in[3];
    const float* rph   = (const float*)d_in[4];
    const float* rpw   = (const float*)d_in[5];
    float* out = (float*)d_out;
    char* ws = (char*)d_ws;

    __bf16*   xbf    = (__bf16*)(ws);                 // 4096*768*2   = 6291456
    __bf16*   WqkvT  = (__bf16*)(ws + 6291456);       // 2304*768*2   = 3538944
    __bf16*   WprojT = (__bf16*)(ws + 9830400);       // 768*768*2    = 1179648
    __bf16*   qb     = (__bf16*)(ws + 11010048);      // 48*1024*64*2 = 6291456
    __bf16*   kb     = (__bf16*)(ws + 17301504);      // 6291456
    _Float16* vtb    = (_Float16*)(ws + 23592960);    // 6291456
    __bf16*   aob    = (__bf16*)(ws + 29884416);      // 4096*768*2   = 6291456
    // total 36175872 bytes

    prep_kernel<<<dim3(3072), dim3(256), 0, stream>>>(x, xbf, Wqkv, WqkvT, Wproj, WprojT);
    gemm_qkv_kernel<<<dim3(32, 24), dim3(256), 0, stream>>>(xbf, WqkvT, qb, kb, vtb);
    attn_kernel<<<dim3(48, 16), dim3(256), 0, stream>>>(qb, kb, vtb, rph, rpw, aob);
    gemm_proj_kernel<<<dim3(64, 12), dim3(256), 0, stream>>>(aob, WprojT, bproj, out);
}

// Round 9
// 137.153 us; speedup vs baseline: 1.0222x; 1.0222x over previous
//
#include <hip/hip_runtime.h>
#include <stddef.h>

// ---------- types ----------
typedef __bf16 bf16x8 __attribute__((ext_vector_type(8)));
typedef __bf16 bf16x4 __attribute__((ext_vector_type(4)));
typedef _Float16 f16x4 __attribute__((ext_vector_type(4)));
typedef float  f32x4  __attribute__((ext_vector_type(4)));

#define MFMA16(a, b, c) __builtin_amdgcn_mfma_f32_16x16x32_bf16((a), (b), (c), 0, 0, 0)
#define MFMA16H(a, b, c) __builtin_amdgcn_mfma_f32_16x16x16f16((a), (b), (c), 0, 0, 0)

// async global->LDS, 16B per lane; LDS dest is wave-uniform base + lane*16
__device__ __forceinline__ void gload_lds16(const void* gsrc, void* ldst) {
    __builtin_amdgcn_global_load_lds(
        (__attribute__((address_space(1))) void*)gsrc,
        (__attribute__((address_space(3))) void*)ldst,
        16, 0, 0);
}

// ---------- K0: fused prep = fp32->bf16 cast of x  +  transpose+cast of both weights ----------
__global__ void prep_kernel(const float* __restrict__ x, __bf16* __restrict__ xbf,
                            const float* __restrict__ Wqkv, __bf16* __restrict__ WqkvT,
                            const float* __restrict__ Wproj, __bf16* __restrict__ WprojT) {
    __shared__ float tile[32][33];
    const int bx = blockIdx.x, tid = threadIdx.x;
    if (bx < 3072) {                       // cast x: 786432 float4 groups
        int i = bx * 256 + tid;
        float4 v = ((const float4*)x)[i];
        bf16x4 o = {(__bf16)v.x, (__bf16)v.y, (__bf16)v.z, (__bf16)v.w};
        ((bf16x4*)xbf)[i] = o;
        return;
    }
    const float* in; __bf16* out; int R, C, c0, r0;
    if (bx < 4800) { int bb = bx - 3072; in = Wqkv;  out = WqkvT;  R = 768; C = 2304;
                     c0 = (bb % 72) * 32; r0 = (bb / 72) * 32; }
    else           { int bb = bx - 4800; in = Wproj; out = WprojT; R = 768; C = 768;
                     c0 = (bb % 24) * 32; r0 = (bb / 24) * 32; }
    const int tx = tid & 31, ty = tid >> 5;    // 32 x 8
#pragma unroll
    for (int i = 0; i < 32; i += 8)
        tile[ty + i][tx] = in[(size_t)(r0 + ty + i) * C + c0 + tx];
    __syncthreads();
#pragma unroll
    for (int i = 0; i < 32; i += 8)
        out[(size_t)(c0 + ty + i) * R + r0 + tx] = (__bf16)tile[tx][ty + i];
}

// ---------- GEMM core: BM x BN tile, BK=64, 256 threads (4 waves, each (BM/2)x(BN/2)) ----------
// POST-MORTEM R5 (BK=32 dbuf, +7.3us): 32-elem LDS rows (64 B) alias banks every 2 rows
// -> frag ds_read_b128 went 4-way-conflicted; and the 12-MFMA compute phase (~130 cyc)
// can't cover L3-hit staging latency (~400+ cyc) anyway since __syncthreads always
// drains vmcnt(0). This 2-barrier BK=64 single-buffer core with 128B rows + 8-chunk
// XOR swizzle is the measured local optimum — co-resident blocks (3/CU) hide the drain.
// POST-MORTEM R8 (LDS-transpose store epilogue, +1.6us): scattered small stores are
// fire-and-forget — they never stalled the wave; coalescing them added serial work.
// LDS rows are 64 elems (8 chunks of 16B); chunk c of row r stored at slot c ^ (r&7).
template<int BM, int BN>
__device__ __forceinline__ void gemm_core_bk64(
    const __bf16* __restrict__ A, const __bf16* __restrict__ Bt, int K,
    int m0, int n0, __bf16* aT, __bf16* bT, f32x4 (&acc)[BM/32][BN/32]) {
    const int tid  = threadIdx.x;
    const int wid  = tid >> 6, lane = tid & 63;
    const int quad = lane >> 4, l16 = lane & 15;
    const int wm = (wid >> 1) * (BM / 2), wn = (wid & 1) * (BN / 2);
    const int r_in = lane >> 3;                    // 0..7
    const int cswz = ((lane & 7) ^ r_in) * 8;      // swizzled k-chunk offset (elems)
    const __bf16* gA = A  + (size_t)(m0 + wid * 8 + r_in) * K + cswz;
    const __bf16* gB = Bt + (size_t)(n0 + wid * 8 + r_in) * K + cswz;
    const int sA = (l16 & 7);
    for (int k0 = 0; k0 < K; k0 += 64) {
        __syncthreads();
#pragma unroll
        for (int j = 0; j < BM / 32; j++)
            gload_lds16(gA + (size_t)(j * 32) * K + k0, aT + (j * 32 + wid * 8) * 64);
#pragma unroll
        for (int j = 0; j < BN / 32; j++)
            gload_lds16(gB + (size_t)(j * 32) * K + k0, bT + (j * 32 + wid * 8) * 64);
        __syncthreads();
#pragma unroll
        for (int kh = 0; kh < 2; kh++) {
            bf16x8 af[BM / 32], bfr[BN / 32];
            const int slot = ((kh * 4 + quad) ^ sA) << 3;
#pragma unroll
            for (int t = 0; t < BM / 32; t++)
                af[t]  = *(const bf16x8*)(aT + (wm + t * 16 + l16) * 64 + slot);
#pragma unroll
            for (int t = 0; t < BN / 32; t++)
                bfr[t] = *(const bf16x8*)(bT + (wn + t * 16 + l16) * 64 + slot);
#pragma unroll
            for (int rt = 0; rt < BM / 32; rt++)
#pragma unroll
                for (int ct = 0; ct < BN / 32; ct++)
                    acc[rt][ct] = MFMA16(af[rt], bfr[ct], acc[rt][ct]);
        }
    }
}

// ---------- K1: QKV GEMM, epilogue scatters to q/k (bh,s,d) bf16 and vT (bh,d,s) f16 ----------
// 128x96 tile, grid (32,24) = 768 blocks = 3/CU uniform (zero scheduling tail).
// K is pre-scaled by 0.125*log2e here (K only feeds QK^T) so the attn inner loop is a
// bare exp2 — Q stays raw because Phase-A rel-bias GEMMs need unscaled Q.
// V writes are s-consecutive per (rt,ct) -> packed f16x4 8B stores (was 4x 2B scalar).
__global__ __launch_bounds__(256, 3)
void gemm_qkv_kernel(const __bf16* __restrict__ A, const __bf16* __restrict__ Bt,
                     __bf16* __restrict__ qb, __bf16* __restrict__ kb,
                     _Float16* __restrict__ vtb) {
    __shared__ __bf16 aT[8192], bT[6144];
    f32x4 acc[4][3];
#pragma unroll
    for (int i = 0; i < 4; i++)
#pragma unroll
        for (int j = 0; j < 3; j++) { f32x4 z = {0.f, 0.f, 0.f, 0.f}; acc[i][j] = z; }
    const int m0 = blockIdx.x * 128, n0 = blockIdx.y * 96;
    gemm_core_bk64<128, 96>(A, Bt, 768, m0, n0, aT, bT, acc);
    const int tid = threadIdx.x, wid = tid >> 6, lane = tid & 63;
    const int quad = lane >> 4, l16 = lane & 15;
    const int wm = (wid >> 1) * 64, wn = (wid & 1) * 48;
    const float KSCALE = 0.18033688f;   // 0.125 * log2(e)
#pragma unroll
    for (int rt = 0; rt < 4; rt++)
#pragma unroll
        for (int ct = 0; ct < 3; ct++) {
            const int ng = n0 + wn + ct * 16 + l16;
            const int which = ng / 768;
            const int rem = ng - which * 768;
            const int hh = rem >> 6, d = rem & 63;
            const int mgb = m0 + wm + rt * 16 + quad * 4;   // 4-aligned row base
            const int b = mgb >> 10, s = mgb & 1023;        // rows 4-aligned, no b crossing
            const int bh = b * 12 + hh;
            if (which == 2) {
                f16x4 vv = {(_Float16)acc[rt][ct][0], (_Float16)acc[rt][ct][1],
                            (_Float16)acc[rt][ct][2], (_Float16)acc[rt][ct][3]};
                *(f16x4*)&vtb[((size_t)bh * 64 + d) * 1024 + s] = vv;
            } else {
#pragma unroll
                for (int r = 0; r < 4; r++) {
                    if (which == 0) qb[((size_t)bh * 1024 + s + r) * 64 + d] = (__bf16)acc[rt][ct][r];
                    else            kb[((size_t)bh * 1024 + s + r) * 64 + d] = (__bf16)(acc[rt][ct][r] * KSCALE);
                }
            }
        }
}

// ---------- K4: proj GEMM + bias, fp32 out ----------
// 64x64 tile, grid (64,12) = 768 blocks = 3/CU uniform.
__global__ __launch_bounds__(256, 3)
void gemm_proj_kernel(const __bf16* __restrict__ A, const __bf16* __restrict__ Bt,
                      const float* __restrict__ bias, float* __restrict__ out) {
    __shared__ __bf16 aT[4096], bT[4096];
    f32x4 acc[2][2];
#pragma unroll
    for (int i = 0; i < 2; i++)
#pragma unroll
        for (int j = 0; j < 2; j++) { f32x4 z = {0.f, 0.f, 0.f, 0.f}; acc[i][j] = z; }
    const int m0 = blockIdx.x * 64, n0 = blockIdx.y * 64;
    gemm_core_bk64<64, 64>(A, Bt, 768, m0, n0, aT, bT, acc);
    const int tid = threadIdx.x, wid = tid >> 6, lane = tid & 63;
    const int quad = lane >> 4, l16 = lane & 15;
    const int wm = (wid >> 1) * 32, wn = (wid & 1) * 32;
#pragma unroll
    for (int rt = 0; rt < 2; rt++)
#pragma unroll
        for (int ct = 0; ct < 2; ct++) {
            const int ng = n0 + wn + ct * 16 + l16;
            const float bb = bias[ng];
#pragma unroll
            for (int r = 0; r < 4; r++) {
                const int mg = m0 + wm + rt * 16 + quad * 4 + r;
                out[(size_t)mg * 768 + ng] = acc[rt][ct][r] + bb;
            }
        }
}

// ---------- K3: attention v7.3 — v7 partition, exp2 softmax, bias in MFMA C-operand ----------
// grid (48 bh, 16 qt), block 256 (4 waves), Q-tile 64, 16 rows/wave.
// bh-fast grid is XCD-optimal (48 % 8 == 0 -> 6 bh x 128 KB/XCD, L2-fit, qt-readers
// co-located). The softmax bias (bhc + bw) is seeded as the S^T MFMA's C-init
// (biasC[2][2] f32x4, 16 adds/iter) instead of added per-element afterward — removes
// 16 fp32 adds/iter/wave from the exp path; exp2 reads sacc directly.
// S^T = MFMA(K-frag, Q-frag): C-layout col=l16=qrow, row=quad*4+r=key — exactly the
// B-frag layout of mfma_f32_16x16x16f16 (k=quad*4+j) -> PV from registers, no P LDS trip.
// K LDS: (key,d) bf16, chunk c of row stored at c^(key&7). V LDS: (d,key) f16, chunk
// kc of row d stored at kc^(d&7) -> b64 A-frag reads are 2-way conflict (free).
// Phase A overlays the K dbuf (16 KB) with Dw[wave][16r][64j] fp32 for rel_w gather.
__global__ __launch_bounds__(256, 3)
void attn_kernel(const __bf16* __restrict__ q, const __bf16* __restrict__ kk,
                 const _Float16* __restrict__ vt, const float* __restrict__ rph,
                 const float* __restrict__ rpw, __bf16* __restrict__ aout) {
    __shared__ __bf16   kbuf2[2][4096];
    __shared__ _Float16 vbuf2[2][4096];
    __shared__ float    relh[64][33];
    const int tid = threadIdx.x, wid = tid >> 6, lane = tid & 63;
    const int quad = lane >> 4, l16 = lane & 15;
    const int bh = blockIdx.x, qt = blockIdx.y;
    const int b = bh / 12, hh = bh - b * 12;
    const int q0 = qt * 64;
    const int w0 = wid * 16;               // wave's first row within the tile
    const int h = qt * 2 + (wid >> 1);     // wave-uniform h coordinate
    const float LOG2E = 1.44269504f;

    // Q fragments: lane holds Q[w0+l16][quad*8+j] — B-frag for S^T, A-frag for Phase A
    const __bf16* qp = q + ((size_t)bh * 1024 + q0 + w0 + l16) * 64;
    bf16x8 aq0 = *(const bf16x8*)(qp + quad * 8);
    bf16x8 aq1 = *(const bf16x8*)(qp + 32 + quad * 8);

    // ---- Phase A: rel_w D-GEMM (Toeplitz) + rel_h GEMM, via MFMA; tables pre-scaled
    // by log2e so the main loop uses native exp2. ----
    float* Dw = ((float*)kbuf2) + wid * 1024;   // 16 rows x 64 cols fp32, per wave
#pragma unroll
    for (int ct = 0; ct < 4; ct++) {
        int j = ct * 16 + l16; if (j > 62) j = 62;
        const float* tb = rpw + (size_t)j * 64;
        float4 t0 = *(const float4*)(tb + quad * 8);
        float4 t1 = *(const float4*)(tb + quad * 8 + 4);
        float4 t2 = *(const float4*)(tb + 32 + quad * 8);
        float4 t3 = *(const float4*)(tb + 32 + quad * 8 + 4);
        bf16x8 b0 = {(__bf16)(t0.x*LOG2E), (__bf16)(t0.y*LOG2E), (__bf16)(t0.z*LOG2E), (__bf16)(t0.w*LOG2E),
                     (__bf16)(t1.x*LOG2E), (__bf16)(t1.y*LOG2E), (__bf16)(t1.z*LOG2E), (__bf16)(t1.w*LOG2E)};
        bf16x8 b1 = {(__bf16)(t2.x*LOG2E), (__bf16)(t2.y*LOG2E), (__bf16)(t2.z*LOG2E), (__bf16)(t2.w*LOG2E),
                     (__bf16)(t3.x*LOG2E), (__bf16)(t3.y*LOG2E), (__bf16)(t3.z*LOG2E), (__bf16)(t3.w*LOG2E)};
        f32x4 z = {0.f, 0.f, 0.f, 0.f};
        z = MFMA16(aq0, b0, z);
        z = MFMA16(aq1, b1, z);
#pragma unroll
        for (int i = 0; i < 4; i++)
            Dw[(quad * 4 + i) * 64 + ct * 16 + l16] = z[i];
    }
#pragma unroll
    for (int ct = 0; ct < 2; ct++) {
        const int tr = h - (ct * 16 + l16) + 31;     // in [0,62]
        const float* tb = rph + (size_t)tr * 64;
        float4 t0 = *(const float4*)(tb + quad * 8);
        float4 t1 = *(const float4*)(tb + quad * 8 + 4);
        float4 t2 = *(const float4*)(tb + 32 + quad * 8);
        float4 t3 = *(const float4*)(tb + 32 + quad * 8 + 4);
        bf16x8 b0 = {(__bf16)(t0.x*LOG2E), (__bf16)(t0.y*LOG2E), (__bf16)(t0.z*LOG2E), (__bf16)(t0.w*LOG2E),
                     (__bf16)(t1.x*LOG2E), (__bf16)(t1.y*LOG2E), (__bf16)(t1.z*LOG2E), (__bf16)(t1.w*LOG2E)};
        bf16x8 b1 = {(__bf16)(t2.x*LOG2E), (__bf16)(t2.y*LOG2E), (__bf16)(t2.z*LOG2E), (__bf16)(t2.w*LOG2E),
                     (__bf16)(t3.x*LOG2E), (__bf16)(t3.y*LOG2E), (__bf16)(t3.z*LOG2E), (__bf16)(t3.w*LOG2E)};
        f32x4 z = {0.f, 0.f, 0.f, 0.f};
        z = MFMA16(aq0, b0, z);
        z = MFMA16(aq1, b1, z);
#pragma unroll
        for (int i = 0; i < 4; i++)
            relh[w0 + quad * 4 + i][ct * 16 + l16] = z[i];
    }
    // gather rel_w biases for lane's qrow (= w0+l16): kw = hf*16 + quad*4 + r
    const int wq = (wid & 1) * 16 + l16;           // w coordinate of lane's qrow
    float bw[2][4];
#pragma unroll
    for (int hf = 0; hf < 2; hf++)
#pragma unroll
        for (int r = 0; r < 4; r++)
            bw[hf][r] = Dw[l16 * 64 + wq + 31 - hf * 16 - quad * 4 - r];
    __syncthreads();   // all gathers done before staging overwrites the Dw overlay

    // ---- main flash loop ----
    f32x4 lacc = {0.f, 0.f, 0.f, 0.f};    // 4 parallel row-sum chains (by r)
    f32x4 o_acc[4];
#pragma unroll
    for (int t = 0; t < 4; t++) { f32x4 z = {0.f, 0.f, 0.f, 0.f}; o_acc[t] = z; }

    const __bf16*   kg0 = kk + (size_t)bh * 65536;
    const _Float16* vg0 = vt + (size_t)bh * 65536;
    const int cbase = wid * 2;                         // 4 waves stage 2 chunks each
    const int srow = lane >> 3;
    const int scol = ((lane & 7) ^ srow) * 8;          // swizzled chunk (8 elems of 16B/8)
    const int swz0 = ((quad ^ (l16 & 7)) << 3);
    const int swz1 = (((quad | 4) ^ (l16 & 7)) << 3);
    const int l7 = l16 & 7, qhi = quad >> 1, qlo = (quad & 1) * 4;

    auto stage = [&](int buf, int kt) {
        const __bf16*   kg = kg0 + kt * 4096;
        const _Float16* vg = vg0 + kt * 64;
        __bf16*   kb_ = &kbuf2[buf][0];
        _Float16* vb_ = &vbuf2[buf][0];
#pragma unroll
        for (int j = 0; j < 2; j++) {
            const int c = cbase + j;
            gload_lds16(kg + (c * 8 + srow) * 64 + scol, kb_ + c * 512);
            gload_lds16(vg + (size_t)(c * 8 + srow) * 1024 + scol, vb_ + c * 512);
        }
    };

    stage(0, 0);
    for (int kt = 0; kt < 16; kt++) {
        const int cur = kt & 1;
        __syncthreads();                 // drains cur's staging
        if (kt < 15) stage(1 - cur, kt + 1);
        const __bf16*   kbuf = &kbuf2[cur][0];
        const _Float16* vbuf = &vbuf2[cur][0];

        // per-iter bias in S^T C-layout: elem r of (ct) = bh(ct>>1) + bw[ct&1][r]
        const float bh0 = relh[w0 + l16][kt * 2];
        const float bh1 = relh[w0 + l16][kt * 2 + 1];
        f32x4 biasC[2][2];
#pragma unroll
        for (int lo = 0; lo < 2; lo++)
#pragma unroll
            for (int r = 0; r < 4; r++) {
                biasC[0][lo][r] = bh0 + bw[lo][r];
                biasC[1][lo][r] = bh1 + bw[lo][r];
            }

        // S^T = K-frag (A) x Q-frag (B), accumulated onto the bias (C-init);
        // K already carries 0.125*log2e
        f32x4 sacc[4];
#pragma unroll
        for (int ct = 0; ct < 4; ct++) {
            const int key = ct * 16 + l16;
            bf16x8 bk0 = *(const bf16x8*)(kbuf + key * 64 + swz0);
            bf16x8 bk1 = *(const bf16x8*)(kbuf + key * 64 + swz1);
            f32x4 z = biasC[ct >> 1][ct & 1];
            z = MFMA16(bk0, aq0, z);
            z = MFMA16(bk1, aq1, z);
            sacc[ct] = z;
        }

        // exp2 directly on biased scores; pack P^T fragments (f16) from registers
        f16x4 pf[4];
#pragma unroll
        for (int ct = 0; ct < 4; ct++)
#pragma unroll
            for (int r = 0; r < 4; r++) {
                float p = __builtin_amdgcn_exp2f(sacc[ct][r]);
                lacc[r] += p;
                pf[ct][r] = (_Float16)p;
            }

        // O^T += V^T * P^T  (16x16x16 f16 MFMAs, V A-frags via b64 LDS reads)
#pragma unroll
        for (int dt = 0; dt < 4; dt++) {
            const int vrow = (dt * 16 + l16) * 64;
#pragma unroll
            for (int ct = 0; ct < 4; ct++) {
                const int slot = (ct * 2 + qhi) ^ l7;
                f16x4 vf = *(const f16x4*)(vbuf + vrow + slot * 8 + qlo);
                o_acc[dt] = MFMA16H(vf, pf[ct], o_acc[dt]);
            }
        }
    }

    // merge the 4 chains, reduce across the 4 quads holding the same qrow, normalize
    float l_run = (lacc[0] + lacc[1]) + (lacc[2] + lacc[3]);
    l_run += __shfl_xor(l_run, 16);
    l_run += __shfl_xor(l_run, 32);
    const float inv = 1.f / l_run;
    const int srow_o = q0 + w0 + l16;
#pragma unroll
    for (int dt = 0; dt < 4; dt++) {
        bf16x4 ov = {(__bf16)(o_acc[dt][0] * inv), (__bf16)(o_acc[dt][1] * inv),
                     (__bf16)(o_acc[dt][2] * inv), (__bf16)(o_acc[dt][3] * inv)};
        *(bf16x4*)&aout[((size_t)b * 1024 + srow_o) * 768 + hh * 64 + dt * 16 + quad * 4] = ov;
    }
}

// ---------- launch ----------
extern "C" void kernel_launch(void* const* d_in, const int* in_sizes, int n_in,
                              void* d_out, int out_size, void* d_ws, size_t ws_size,
                              hipStream_t stream) {
    const float* x     = (const float*)d_in[0];
    const float* Wqkv  = (const float*)d_in[1];
    const float* Wproj = (const float*)d_in[2];
    const float* bproj = (const float*)d_in[3];
    const float* rph   = (const float*)d_in[4];
    const float* rpw   = (const float*)d_in[5];
    float* out = (float*)d_out;
    char* ws = (char*)d_ws;

    __bf16*   xbf    = (__bf16*)(ws);                 // 4096*768*2   = 6291456
    __bf16*   WqkvT  = (__bf16*)(ws + 6291456);       // 2304*768*2   = 3538944
    __bf16*   WprojT = (__bf16*)(ws + 9830400);       // 768*768*2    = 1179648
    __bf16*   qb     = (__bf16*)(ws + 11010048);      // 48*1024*64*2 = 6291456
    __bf16*   kb     = (__bf16*)(ws + 17301504);      // 6291456
    _Float16* vtb    = (_Float16*)(ws + 23592960);    // 6291456
    __bf16*   aob    = (__bf16*)(ws + 29884416);      // 4096*768*2   = 6291456
    // total 36175872 bytes

    prep_kernel<<<dim3(5376), dim3(256), 0, stream>>>(x, xbf, Wqkv, WqkvT, Wproj, WprojT);
    gemm_qkv_kernel<<<dim3(32, 24), dim3(256), 0, stream>>>(xbf, WqkvT, qb, kb, vtb);
    attn_kernel<<<dim3(48, 16), dim3(256), 0, stream>>>(qb, kb, vtb, rph, rpw, aob);
    gemm_proj_kernel<<<dim3(64, 12), dim3(256), 0, stream>>>(aob, WprojT, bproj, out);
}